// Round 1
// baseline (1162.023 us; speedup 1.0000x reference)
//
#include <hip/hip_runtime.h>
#include <hip/hip_bf16.h>

#define IN_F 4096
#define OUT_F 4096
#define M_TOK 8192
#define RANK 16

typedef __attribute__((ext_vector_type(4))) float f32x4;
typedef __attribute__((ext_vector_type(8))) short short8;

struct alignas(16) bf16x8_s { __hip_bfloat16 v[8]; };
struct alignas(8)  bf16x4_s { __hip_bfloat16 v[4]; };

// ---------------------------------------------------------------------------
// Kernel 1: dequantize int4-coded weights (stored as int32 in [0,15]) to bf16.
// W[o][i] = bf16(scales[o][i/64] * (q - 8)).  8 elements / thread.
// ---------------------------------------------------------------------------
__global__ void dequant_kernel(const int* __restrict__ q,
                               const float* __restrict__ scales,
                               __hip_bfloat16* __restrict__ W) {
    size_t tid  = (size_t)blockIdx.x * blockDim.x + threadIdx.x;
    size_t base = tid * 8;                       // flat element index
    int o = (int)(base >> 12);                   // / 4096
    int i = (int)(base & 4095);
    float s = scales[o * 64 + (i >> 6)];
    const int4* qp = (const int4*)(q + base);
    int4 q0 = qp[0];
    int4 q1 = qp[1];
    bf16x8_s r;
    r.v[0] = __float2bfloat16(s * (float)(q0.x - 8));
    r.v[1] = __float2bfloat16(s * (float)(q0.y - 8));
    r.v[2] = __float2bfloat16(s * (float)(q0.z - 8));
    r.v[3] = __float2bfloat16(s * (float)(q0.w - 8));
    r.v[4] = __float2bfloat16(s * (float)(q1.x - 8));
    r.v[5] = __float2bfloat16(s * (float)(q1.y - 8));
    r.v[6] = __float2bfloat16(s * (float)(q1.z - 8));
    r.v[7] = __float2bfloat16(s * (float)(q1.w - 8));
    *(bf16x8_s*)(W + base) = r;
}

// ---------------------------------------------------------------------------
// Kernel 2: convert x fp32 -> bf16 (for MFMA) and compute xa = x @ lora_A
// in fp32.  4 rows per block (one wave per row) so lora_A (256 KB) re-reads
// are served by L1/L2.
// ---------------------------------------------------------------------------
__global__ void xprep_kernel(const float* __restrict__ x,
                             const float* __restrict__ A,
                             __hip_bfloat16* __restrict__ xb,
                             float* __restrict__ xa) {
    int row  = threadIdx.x >> 6;                 // 0..3 (one wave per row)
    int lane = threadIdx.x & 63;
    int m = blockIdx.x * 4 + row;
    const float* xr = x + (size_t)m * IN_F;
    __hip_bfloat16* xbr = xb + (size_t)m * IN_F;

    float acc[RANK];
#pragma unroll
    for (int r = 0; r < RANK; ++r) acc[r] = 0.f;

    for (int c = 0; c < 16; ++c) {
        int i = (c * 64 + lane) * 4;             // 4 consecutive floats
        float4 xv = *(const float4*)(xr + i);
        bf16x4_s bo;
        bo.v[0] = __float2bfloat16(xv.x);
        bo.v[1] = __float2bfloat16(xv.y);
        bo.v[2] = __float2bfloat16(xv.z);
        bo.v[3] = __float2bfloat16(xv.w);
        *(bf16x4_s*)(xbr + i) = bo;
        const float* Ap = A + (size_t)i * RANK;  // lora_A is [IN_F][RANK]
        float xe[4] = {xv.x, xv.y, xv.z, xv.w};
#pragma unroll
        for (int e = 0; e < 4; ++e) {
#pragma unroll
            for (int r = 0; r < RANK; ++r)
                acc[r] += xe[e] * Ap[e * RANK + r];
        }
    }
    // wave(64)-wide reduction of the 16 partial sums
#pragma unroll
    for (int r = 0; r < RANK; ++r) {
#pragma unroll
        for (int off = 32; off > 0; off >>= 1)
            acc[r] += __shfl_down(acc[r], off);
    }
    if (lane == 0) {
#pragma unroll
        for (int r = 0; r < RANK; ++r) xa[(size_t)m * RANK + r] = acc[r];
    }
}

// ---------------------------------------------------------------------------
// Kernel 3: main GEMM (m97 structure): out[m][n] =
//   sum_k xb[m][k]*W[n][k] + bias[n] + 2 * sum_r xa[m][r]*lora_B[r][n]
// 128x128 tile, BK=64, 256 threads = 4 waves (2x2), 4x4 mfma 16x16x32 / wave.
// ---------------------------------------------------------------------------
__global__ __launch_bounds__(256) void qlora_gemm_kernel(
    const __hip_bfloat16* __restrict__ xb,   // [M_TOK][IN_F]
    const __hip_bfloat16* __restrict__ Wq,   // [OUT_F][IN_F]  (B^T layout)
    const float* __restrict__ bias,          // [OUT_F]
    const float* __restrict__ xa,            // [M_TOK][RANK]
    const float* __restrict__ lB,            // [RANK][OUT_F]
    float* __restrict__ out) {               // [M_TOK][OUT_F]
    __shared__ __hip_bfloat16 As[128 * 64];  // 16 KB
    __shared__ __hip_bfloat16 Bs[128 * 64];  // 16 KB
    __shared__ float xa_s[128 * 16];         // 8 KB
    __shared__ float lb_s[16 * 128];         // 8 KB (pre-scaled by 2.0)

    const int tid  = threadIdx.x;
    const int wave = tid >> 6;
    const int lane = tid & 63;
    const int wm = wave >> 1;                // 0..1
    const int wn = wave & 1;                 // 0..1
    const int m0 = blockIdx.y * 128;
    const int n0 = blockIdx.x * 128;

    // stage lora tiles once per block (read in epilogue, after many barriers)
    for (int idx = tid; idx < 128 * 16; idx += 256) {
        xa_s[idx] = xa[(size_t)m0 * RANK + idx];
        int j = idx >> 7, nl = idx & 127;
        lb_s[idx] = 2.0f * lB[(size_t)j * OUT_F + n0 + nl];
    }

    f32x4 acc[4][4];
#pragma unroll
    for (int i = 0; i < 4; ++i)
#pragma unroll
        for (int j = 0; j < 4; ++j) acc[i][j] = (f32x4){0.f, 0.f, 0.f, 0.f};

    const int sr = lane >> 3;                // 0..7 sub-row within 8-row chunk
    const int sc = (lane & 7) * 8;           // 0..56 bf16-col, 16B granules

    for (int k0 = 0; k0 < IN_F; k0 += 64) {
        // ---- stage A/B tiles: global -> LDS, 16B/lane, wave-uniform LDS base
#pragma unroll
        for (int i = 0; i < 4; ++i) {
            int c = i * 4 + wave;            // chunk 0..15 = rows [c*8, c*8+8)
            const __hip_bfloat16* ag =
                xb + (size_t)(m0 + c * 8 + sr) * IN_F + k0 + sc;
            const __hip_bfloat16* bg =
                Wq + (size_t)(n0 + c * 8 + sr) * IN_F + k0 + sc;
            __builtin_amdgcn_global_load_lds(
                (const __attribute__((address_space(1))) void*)ag,
                (__attribute__((address_space(3))) void*)(As + c * 512), 16, 0, 0);
            __builtin_amdgcn_global_load_lds(
                (const __attribute__((address_space(1))) void*)bg,
                (__attribute__((address_space(3))) void*)(Bs + c * 512), 16, 0, 0);
        }
        __syncthreads();                     // drains vmcnt before reads

        const short* Asp = (const short*)As;
        const short* Bsp = (const short*)Bs;
#pragma unroll
        for (int ks = 0; ks < 2; ++ks) {
            short8 af[4], bfv[4];
            const int col = ks * 32 + (lane >> 4) * 8;
            const int ar  = wm * 64 + (lane & 15);
            const int br  = wn * 64 + (lane & 15);
#pragma unroll
            for (int t = 0; t < 4; ++t) {
                af[t]  = *(const short8*)(Asp + (ar + t * 16) * 64 + col);
                bfv[t] = *(const short8*)(Bsp + (br + t * 16) * 64 + col);
            }
#pragma unroll
            for (int i = 0; i < 4; ++i)
#pragma unroll
                for (int j = 0; j < 4; ++j)
                    acc[i][j] = __builtin_amdgcn_mfma_f32_16x16x32_bf16(
                        af[i], bfv[j], acc[i][j], 0, 0, 0);
        }
        __syncthreads();                     // protect LDS for next stage
    }

    // ---- epilogue: rank-16 LoRA outer-product + bias, then store
    // C/D layout (16x16x32): col = lane&15, row = (lane>>4)*4 + reg
    const int lrow = (lane >> 4) * 4;
    const int lcol = lane & 15;
#pragma unroll
    for (int j = 0; j < RANK; ++j) {
        float lb[4];
#pragma unroll
        for (int nt = 0; nt < 4; ++nt)
            lb[nt] = lb_s[j * 128 + wn * 64 + nt * 16 + lcol];
#pragma unroll
        for (int mt = 0; mt < 4; ++mt)
#pragma unroll
            for (int r = 0; r < 4; ++r) {
                float xv = xa_s[(wm * 64 + mt * 16 + lrow + r) * RANK + j];
#pragma unroll
                for (int nt = 0; nt < 4; ++nt) acc[mt][nt][r] += xv * lb[nt];
            }
    }
#pragma unroll
    for (int nt = 0; nt < 4; ++nt) {
        const int n = n0 + wn * 64 + nt * 16 + lcol;
        const float bv = bias[n];
#pragma unroll
        for (int mt = 0; mt < 4; ++mt)
#pragma unroll
            for (int r = 0; r < 4; ++r) {
                const int m = m0 + wm * 64 + mt * 16 + lrow + r;
                out[(size_t)m * OUT_F + n] = acc[mt][nt][r] + bv;
            }
    }
}

// ---------------------------------------------------------------------------
extern "C" void kernel_launch(void* const* d_in, const int* in_sizes, int n_in,
                              void* d_out, int out_size, void* d_ws, size_t ws_size,
                              hipStream_t stream) {
    const float* x      = (const float*)d_in[0];   // [8,1024,4096] fp32
    const int*   qw     = (const int*)  d_in[1];   // [4096,4096] int32 codes
    const float* scales = (const float*)d_in[2];   // [4096,64] fp32
    const float* bias   = (const float*)d_in[3];   // [4096] fp32
    const float* lA     = (const float*)d_in[4];   // [4096,16] fp32
    const float* lB     = (const float*)d_in[5];   // [16,4096] fp32
    float* out = (float*)d_out;                    // [8,1024,4096] fp32

    // workspace layout (needs ~96.5 MB)
    char* ws = (char*)d_ws;
    __hip_bfloat16* Wq = (__hip_bfloat16*)ws;                              // 32 MB
    __hip_bfloat16* xb = (__hip_bfloat16*)(ws + (size_t)32 * 1024 * 1024); // 64 MB
    float*          xa = (float*)(ws + (size_t)96 * 1024 * 1024);          // 512 KB

    // 1) dequant weights: 4096*4096/8 threads
    dequant_kernel<<<8192, 256, 0, stream>>>(qw, scales, Wq);
    // 2) x -> bf16 + x @ lora_A : 4 rows / block
    xprep_kernel<<<M_TOK / 4, 256, 0, stream>>>(x, lA, xb, xa);
    // 3) main GEMM + fused bias/LoRA epilogue
    dim3 grid(OUT_F / 128, M_TOK / 128);           // (32, 64)
    qlora_gemm_kernel<<<grid, 256, 0, stream>>>(xb, Wq, bias, xa, lB, out);
}

// Round 2
// 690.813 us; speedup vs baseline: 1.6821x; 1.6821x over previous
//
#include <hip/hip_runtime.h>
#include <hip/hip_bf16.h>

#define IN_F 4096
#define OUT_F 4096
#define M_TOK 8192
#define RANK 16

typedef __attribute__((ext_vector_type(4))) float f32x4;
typedef __attribute__((ext_vector_type(8))) short short8;

struct alignas(16) bf16x8_s { __hip_bfloat16 v[8]; };

// ---------------------------------------------------------------------------
// Kernel 1: dequant int4 codes -> bf16, with the rank-16 LoRA folded in:
//   W[o][i] = bf16( scales[o][i/64]*(q-8) + 2 * sum_r A[i][r]*B[r][o] )
// Thread: 8 consecutive i for 4 consecutive o (A-loads reused 4x).
// o is block-uniform-ish (4 per block) -> B[r][o] loads are cheap broadcasts.
// ---------------------------------------------------------------------------
__global__ void dequant_fold_kernel(const int* __restrict__ q,
                                    const float* __restrict__ scales,
                                    const float* __restrict__ lA,   // [IN_F][RANK]
                                    const float* __restrict__ lB,   // [RANK][OUT_F]
                                    __hip_bfloat16* __restrict__ W) {
    const int tid = threadIdx.x;
    const int ob = blockIdx.x >> 1;          // 0..1023
    const int ih = blockIdx.x & 1;
    const int o0 = ob * 4;
    const int i0 = ih * 2048 + tid * 8;

    float acc[4][8];
#pragma unroll
    for (int oi = 0; oi < 4; ++oi)
#pragma unroll
        for (int e = 0; e < 8; ++e) acc[oi][e] = 0.f;

#pragma unroll
    for (int rq = 0; rq < 4; ++rq) {
        float4 Ar[8];
#pragma unroll
        for (int e = 0; e < 8; ++e)
            Ar[e] = *(const float4*)(lA + (size_t)(i0 + e) * RANK + rq * 4);
#pragma unroll
        for (int oi = 0; oi < 4; ++oi) {
            const int o = o0 + oi;
            const float b0 = lB[(size_t)(rq * 4 + 0) * OUT_F + o];
            const float b1 = lB[(size_t)(rq * 4 + 1) * OUT_F + o];
            const float b2 = lB[(size_t)(rq * 4 + 2) * OUT_F + o];
            const float b3 = lB[(size_t)(rq * 4 + 3) * OUT_F + o];
#pragma unroll
            for (int e = 0; e < 8; ++e)
                acc[oi][e] += Ar[e].x * b0 + Ar[e].y * b1 + Ar[e].z * b2 + Ar[e].w * b3;
        }
    }

#pragma unroll
    for (int oi = 0; oi < 4; ++oi) {
        const int o = o0 + oi;
        const float s = scales[o * 64 + (i0 >> 6)];
        const int4* qp = (const int4*)(q + (size_t)o * IN_F + i0);
        int4 q0 = qp[0];
        int4 q1 = qp[1];
        bf16x8_s r;
        r.v[0] = __float2bfloat16(s * (float)(q0.x - 8) + 2.f * acc[oi][0]);
        r.v[1] = __float2bfloat16(s * (float)(q0.y - 8) + 2.f * acc[oi][1]);
        r.v[2] = __float2bfloat16(s * (float)(q0.z - 8) + 2.f * acc[oi][2]);
        r.v[3] = __float2bfloat16(s * (float)(q0.w - 8) + 2.f * acc[oi][3]);
        r.v[4] = __float2bfloat16(s * (float)(q1.x - 8) + 2.f * acc[oi][4]);
        r.v[5] = __float2bfloat16(s * (float)(q1.y - 8) + 2.f * acc[oi][5]);
        r.v[6] = __float2bfloat16(s * (float)(q1.z - 8) + 2.f * acc[oi][6]);
        r.v[7] = __float2bfloat16(s * (float)(q1.w - 8) + 2.f * acc[oi][7]);
        *(bf16x8_s*)(W + (size_t)o * IN_F + i0) = r;
    }
}

// ---------------------------------------------------------------------------
// Kernel 2: pure streaming convert x fp32 -> bf16 (for MFMA A operand).
// ---------------------------------------------------------------------------
__global__ void convert_kernel(const float* __restrict__ x,
                               __hip_bfloat16* __restrict__ xb) {
    size_t base = ((size_t)blockIdx.x * blockDim.x + threadIdx.x) * 8;
    float4 v0 = *(const float4*)(x + base);
    float4 v1 = *(const float4*)(x + base + 4);
    bf16x8_s r;
    r.v[0] = __float2bfloat16(v0.x);
    r.v[1] = __float2bfloat16(v0.y);
    r.v[2] = __float2bfloat16(v0.z);
    r.v[3] = __float2bfloat16(v0.w);
    r.v[4] = __float2bfloat16(v1.x);
    r.v[5] = __float2bfloat16(v1.y);
    r.v[6] = __float2bfloat16(v1.z);
    r.v[7] = __float2bfloat16(v1.w);
    *(bf16x8_s*)(xb + base) = r;
}

// ---------------------------------------------------------------------------
// Kernel 3: main GEMM (m97 structure + XOR bank swizzle):
//   out[m][n] = sum_k xb[m][k]*W[n][k] + bias[n]
// 128x128 tile, BK=64, 256 threads = 4 waves (2x2), 4x4 mfma 16x16x32 / wave.
//
// LDS layout: row-major K-major tile, 64 shorts (128 B = exactly 32 banks)
// per row, with the 16B granule column XOR-swizzled by (row&7):
//   granule(row, colg) lives at  row*64 + ((colg ^ (row&7)) * 8)  shorts.
// global_load_lds writes lane -> base + lane*16B, so the swizzle is applied
// on the *global source* column each lane fetches. Fragment reads then hit
// all 8 bank-quads (2 lanes/quad = conflict-free, m136).
// ---------------------------------------------------------------------------
__global__ __launch_bounds__(256) void qlora_gemm_kernel(
    const __hip_bfloat16* __restrict__ xb,   // [M_TOK][IN_F]
    const __hip_bfloat16* __restrict__ Wq,   // [OUT_F][IN_F]  (B^T layout)
    const float* __restrict__ bias,          // [OUT_F]
    float* __restrict__ out) {               // [M_TOK][OUT_F]
    __shared__ __hip_bfloat16 As[128 * 64];  // 16 KB
    __shared__ __hip_bfloat16 Bs[128 * 64];  // 16 KB

    const int tid  = threadIdx.x;
    const int wave = tid >> 6;
    const int lane = tid & 63;
    const int wm = wave >> 1;                // 0..1
    const int wn = wave & 1;                 // 0..1
    const int m0 = blockIdx.y * 128;
    const int n0 = blockIdx.x * 128;

    f32x4 acc[4][4];
#pragma unroll
    for (int i = 0; i < 4; ++i)
#pragma unroll
        for (int j = 0; j < 4; ++j) acc[i][j] = (f32x4){0.f, 0.f, 0.f, 0.f};

    // staging source: lane (sr, gc) fetches global granule (gc ^ sr) of row sr
    const int sr = lane >> 3;                // 0..7 sub-row within 8-row chunk
    const int sc = ((lane & 7) ^ sr) * 8;    // swizzled 16B-granule column

    for (int k0 = 0; k0 < IN_F; k0 += 64) {
#pragma unroll
        for (int i = 0; i < 4; ++i) {
            int c = i * 4 + wave;            // chunk 0..15 = rows [c*8, c*8+8)
            const __hip_bfloat16* ag =
                xb + (size_t)(m0 + c * 8 + sr) * IN_F + k0 + sc;
            const __hip_bfloat16* bg =
                Wq + (size_t)(n0 + c * 8 + sr) * IN_F + k0 + sc;
            __builtin_amdgcn_global_load_lds(
                (const __attribute__((address_space(1))) void*)ag,
                (__attribute__((address_space(3))) void*)(As + c * 512), 16, 0, 0);
            __builtin_amdgcn_global_load_lds(
                (const __attribute__((address_space(1))) void*)bg,
                (__attribute__((address_space(3))) void*)(Bs + c * 512), 16, 0, 0);
        }
        __syncthreads();                     // drains vmcnt before reads

        const short* Asp = (const short*)As;
        const short* Bsp = (const short*)Bs;
        const int ar = wm * 64 + (lane & 15);
        const int br = wn * 64 + (lane & 15);
#pragma unroll
        for (int ks = 0; ks < 2; ++ks) {
            // fragment granule column, then apply the XOR swizzle.
            // (row & 7) == (lane & 7) for every t since t*16 % 8 == 0.
            const int colg = ks * 4 + (lane >> 4);
            const int csw  = (colg ^ (lane & 7)) * 8;   // swizzled short offset
            short8 af[4], bfv[4];
#pragma unroll
            for (int t = 0; t < 4; ++t) {
                af[t]  = *(const short8*)(Asp + (ar + t * 16) * 64 + csw);
                bfv[t] = *(const short8*)(Bsp + (br + t * 16) * 64 + csw);
            }
#pragma unroll
            for (int i = 0; i < 4; ++i)
#pragma unroll
                for (int j = 0; j < 4; ++j)
                    acc[i][j] = __builtin_amdgcn_mfma_f32_16x16x32_bf16(
                        af[i], bfv[j], acc[i][j], 0, 0, 0);
        }
        __syncthreads();                     // protect LDS for next stage
    }

    // ---- epilogue: bias + store
    // C/D layout (16x16x32): col = lane&15, row = (lane>>4)*4 + reg
    const int lrow = (lane >> 4) * 4;
    const int lcol = lane & 15;
#pragma unroll
    for (int nt = 0; nt < 4; ++nt) {
        const int n = n0 + wn * 64 + nt * 16 + lcol;
        const float bv = bias[n];
#pragma unroll
        for (int mt = 0; mt < 4; ++mt)
#pragma unroll
            for (int r = 0; r < 4; ++r) {
                const int m = m0 + wm * 64 + mt * 16 + lrow + r;
                out[(size_t)m * OUT_F + n] = acc[mt][nt][r] + bv;
            }
    }
}

// ---------------------------------------------------------------------------
extern "C" void kernel_launch(void* const* d_in, const int* in_sizes, int n_in,
                              void* d_out, int out_size, void* d_ws, size_t ws_size,
                              hipStream_t stream) {
    const float* x      = (const float*)d_in[0];   // [8,1024,4096] fp32
    const int*   qw     = (const int*)  d_in[1];   // [4096,4096] int32 codes
    const float* scales = (const float*)d_in[2];   // [4096,64] fp32
    const float* bias   = (const float*)d_in[3];   // [4096] fp32
    const float* lA     = (const float*)d_in[4];   // [4096,16] fp32
    const float* lB     = (const float*)d_in[5];   // [16,4096] fp32
    float* out = (float*)d_out;                    // [8,1024,4096] fp32

    // workspace layout (needs 96 MB)
    char* ws = (char*)d_ws;
    __hip_bfloat16* Wq = (__hip_bfloat16*)ws;                              // 32 MB
    __hip_bfloat16* xb = (__hip_bfloat16*)(ws + (size_t)32 * 1024 * 1024); // 64 MB

    // 1) dequant + LoRA fold: 4 o x 2048 i per block
    dequant_fold_kernel<<<2048, 256, 0, stream>>>(qw, scales, lA, lB, Wq);
    // 2) x -> bf16 streaming convert
    convert_kernel<<<M_TOK * IN_F / (8 * 256), 256, 0, stream>>>(x, xb);
    // 3) main GEMM + bias epilogue
    dim3 grid(OUT_F / 128, M_TOK / 128);           // (32, 64)
    qlora_gemm_kernel<<<grid, 256, 0, stream>>>(xb, Wq, bias, out);
}

// Round 3
// 667.695 us; speedup vs baseline: 1.7404x; 1.0346x over previous
//
#include <hip/hip_runtime.h>
#include <hip/hip_bf16.h>

#define IN_F 4096
#define OUT_F 4096
#define M_TOK 8192
#define RANK 16

#define CONV_BLOCKS (M_TOK * IN_F / (8 * 256))   // 16384
#define DEQ_BLOCKS  2048

typedef __attribute__((ext_vector_type(4))) float f32x4;
typedef __attribute__((ext_vector_type(8))) short short8;

struct alignas(16) bf16x8_s { __hip_bfloat16 v[8]; };

// ---------------------------------------------------------------------------
// Kernel 1 (merged prep):
//  blocks [0, CONV_BLOCKS): streaming convert x fp32 -> bf16
//  blocks [CONV_BLOCKS, +DEQ_BLOCKS): dequant int4 codes -> bf16 with the
//    rank-16 LoRA folded in:
//    W[o][i] = bf16( scales[o][i/64]*(q-8) + 2*sum_r A[i][r]*B[r][o] )
//  dequant thread: 8 consecutive i x 4 consecutive o. lA rows are loaded as
//  4 consecutive float4 (full 64B line consumed at once); lB coefficients are
//  block-uniform -> scalar loads.
// ---------------------------------------------------------------------------
__global__ __launch_bounds__(256) void prep_kernel(
    const float* __restrict__ x,
    const int* __restrict__ q,
    const float* __restrict__ scales,
    const float* __restrict__ lA,   // [IN_F][RANK]
    const float* __restrict__ lB,   // [RANK][OUT_F]
    __hip_bfloat16* __restrict__ xb,
    __hip_bfloat16* __restrict__ W) {
    const int tid = threadIdx.x;

    if (blockIdx.x < CONV_BLOCKS) {
        // ---------------- streaming fp32 -> bf16 convert ----------------
        size_t base = ((size_t)blockIdx.x * 256 + tid) * 8;
        float4 v0 = *(const float4*)(x + base);
        float4 v1 = *(const float4*)(x + base + 4);
        bf16x8_s r;
        r.v[0] = __float2bfloat16(v0.x);
        r.v[1] = __float2bfloat16(v0.y);
        r.v[2] = __float2bfloat16(v0.z);
        r.v[3] = __float2bfloat16(v0.w);
        r.v[4] = __float2bfloat16(v1.x);
        r.v[5] = __float2bfloat16(v1.y);
        r.v[6] = __float2bfloat16(v1.z);
        r.v[7] = __float2bfloat16(v1.w);
        *(bf16x8_s*)(xb + base) = r;
        return;
    }

    // ---------------- dequant + LoRA fold ----------------
    const int bid = blockIdx.x - CONV_BLOCKS;    // 0..2047
    const int o0 = (bid >> 1) * 4;               // block-uniform
    const int i0 = (bid & 1) * 2048 + tid * 8;

    // lB coefficients (pre-scaled by 2): wave-uniform -> scalar loads.
    float bw[16][4];
#pragma unroll
    for (int r = 0; r < 16; ++r)
#pragma unroll
        for (int oi = 0; oi < 4; ++oi)
            bw[r][oi] = 2.0f * lB[(size_t)r * OUT_F + o0 + oi];

    // fold[oi][e] = 2 * sum_r lA[i0+e][r] * lB[r][o0+oi]
    float fold[4][8];
#pragma unroll
    for (int e = 0; e < 8; ++e) {
        const float* ar = lA + (size_t)(i0 + e) * RANK;
        float4 a0 = *(const float4*)(ar + 0);
        float4 a1 = *(const float4*)(ar + 4);
        float4 a2 = *(const float4*)(ar + 8);
        float4 a3 = *(const float4*)(ar + 12);
#pragma unroll
        for (int oi = 0; oi < 4; ++oi) {
            float f = a0.x * bw[0][oi] + a0.y * bw[1][oi]
                    + a0.z * bw[2][oi] + a0.w * bw[3][oi]
                    + a1.x * bw[4][oi] + a1.y * bw[5][oi]
                    + a1.z * bw[6][oi] + a1.w * bw[7][oi]
                    + a2.x * bw[8][oi] + a2.y * bw[9][oi]
                    + a2.z * bw[10][oi] + a2.w * bw[11][oi]
                    + a3.x * bw[12][oi] + a3.y * bw[13][oi]
                    + a3.z * bw[14][oi] + a3.w * bw[15][oi];
            fold[oi][e] = f;
        }
    }

#pragma unroll
    for (int oi = 0; oi < 4; ++oi) {
        const int o = o0 + oi;
        const float s = scales[o * 64 + (i0 >> 6)];
        const int4* qp = (const int4*)(q + (size_t)o * IN_F + i0);
        int4 q0 = qp[0];
        int4 q1 = qp[1];
        bf16x8_s r;
        r.v[0] = __float2bfloat16(s * (float)(q0.x - 8) + fold[oi][0]);
        r.v[1] = __float2bfloat16(s * (float)(q0.y - 8) + fold[oi][1]);
        r.v[2] = __float2bfloat16(s * (float)(q0.z - 8) + fold[oi][2]);
        r.v[3] = __float2bfloat16(s * (float)(q0.w - 8) + fold[oi][3]);
        r.v[4] = __float2bfloat16(s * (float)(q1.x - 8) + fold[oi][4]);
        r.v[5] = __float2bfloat16(s * (float)(q1.y - 8) + fold[oi][5]);
        r.v[6] = __float2bfloat16(s * (float)(q1.z - 8) + fold[oi][6]);
        r.v[7] = __float2bfloat16(s * (float)(q1.w - 8) + fold[oi][7]);
        *(bf16x8_s*)(W + (size_t)o * IN_F + i0) = r;
    }
}

// ---------------------------------------------------------------------------
// Kernel 2: main GEMM (m97 structure + XOR bank swizzle) — UNCHANGED from R2
// (at the m97 plateau: MfmaUtil 33%, conflicts 0).
//   out[m][n] = sum_k xb[m][k]*W[n][k] + bias[n]
// ---------------------------------------------------------------------------
__global__ __launch_bounds__(256) void qlora_gemm_kernel(
    const __hip_bfloat16* __restrict__ xb,   // [M_TOK][IN_F]
    const __hip_bfloat16* __restrict__ Wq,   // [OUT_F][IN_F]  (B^T layout)
    const float* __restrict__ bias,          // [OUT_F]
    float* __restrict__ out) {               // [M_TOK][OUT_F]
    __shared__ __hip_bfloat16 As[128 * 64];  // 16 KB
    __shared__ __hip_bfloat16 Bs[128 * 64];  // 16 KB

    const int tid  = threadIdx.x;
    const int wave = tid >> 6;
    const int lane = tid & 63;
    const int wm = wave >> 1;                // 0..1
    const int wn = wave & 1;                 // 0..1
    const int m0 = blockIdx.y * 128;
    const int n0 = blockIdx.x * 128;

    f32x4 acc[4][4];
#pragma unroll
    for (int i = 0; i < 4; ++i)
#pragma unroll
        for (int j = 0; j < 4; ++j) acc[i][j] = (f32x4){0.f, 0.f, 0.f, 0.f};

    // staging source: lane (sr, gc) fetches global granule (gc ^ sr) of row sr
    const int sr = lane >> 3;                // 0..7 sub-row within 8-row chunk
    const int sc = ((lane & 7) ^ sr) * 8;    // swizzled 16B-granule column

    for (int k0 = 0; k0 < IN_F; k0 += 64) {
#pragma unroll
        for (int i = 0; i < 4; ++i) {
            int c = i * 4 + wave;            // chunk 0..15 = rows [c*8, c*8+8)
            const __hip_bfloat16* ag =
                xb + (size_t)(m0 + c * 8 + sr) * IN_F + k0 + sc;
            const __hip_bfloat16* bg =
                Wq + (size_t)(n0 + c * 8 + sr) * IN_F + k0 + sc;
            __builtin_amdgcn_global_load_lds(
                (const __attribute__((address_space(1))) void*)ag,
                (__attribute__((address_space(3))) void*)(As + c * 512), 16, 0, 0);
            __builtin_amdgcn_global_load_lds(
                (const __attribute__((address_space(1))) void*)bg,
                (__attribute__((address_space(3))) void*)(Bs + c * 512), 16, 0, 0);
        }
        __syncthreads();                     // drains vmcnt before reads

        const short* Asp = (const short*)As;
        const short* Bsp = (const short*)Bs;
        const int ar = wm * 64 + (lane & 15);
        const int br = wn * 64 + (lane & 15);
#pragma unroll
        for (int ks = 0; ks < 2; ++ks) {
            const int colg = ks * 4 + (lane >> 4);
            const int csw  = (colg ^ (lane & 7)) * 8;   // swizzled short offset
            short8 af[4], bfv[4];
#pragma unroll
            for (int t = 0; t < 4; ++t) {
                af[t]  = *(const short8*)(Asp + (ar + t * 16) * 64 + csw);
                bfv[t] = *(const short8*)(Bsp + (br + t * 16) * 64 + csw);
            }
#pragma unroll
            for (int i = 0; i < 4; ++i)
#pragma unroll
                for (int j = 0; j < 4; ++j)
                    acc[i][j] = __builtin_amdgcn_mfma_f32_16x16x32_bf16(
                        af[i], bfv[j], acc[i][j], 0, 0, 0);
        }
        __syncthreads();                     // protect LDS for next stage
    }

    // ---- epilogue: bias + store
    // C/D layout (16x16x32): col = lane&15, row = (lane>>4)*4 + reg
    const int lrow = (lane >> 4) * 4;
    const int lcol = lane & 15;
#pragma unroll
    for (int nt = 0; nt < 4; ++nt) {
        const int n = n0 + wn * 64 + nt * 16 + lcol;
        const float bv = bias[n];
#pragma unroll
        for (int mt = 0; mt < 4; ++mt)
#pragma unroll
            for (int r = 0; r < 4; ++r) {
                const int m = m0 + wm * 64 + mt * 16 + lrow + r;
                out[(size_t)m * OUT_F + n] = acc[mt][nt][r] + bv;
            }
    }
}

// ---------------------------------------------------------------------------
extern "C" void kernel_launch(void* const* d_in, const int* in_sizes, int n_in,
                              void* d_out, int out_size, void* d_ws, size_t ws_size,
                              hipStream_t stream) {
    const float* x      = (const float*)d_in[0];   // [8,1024,4096] fp32
    const int*   qw     = (const int*)  d_in[1];   // [4096,4096] int32 codes
    const float* scales = (const float*)d_in[2];   // [4096,64] fp32
    const float* bias   = (const float*)d_in[3];   // [4096] fp32
    const float* lA     = (const float*)d_in[4];   // [4096,16] fp32
    const float* lB     = (const float*)d_in[5];   // [16,4096] fp32
    float* out = (float*)d_out;                    // [8,1024,4096] fp32

    // workspace layout (needs 96 MB)
    char* ws = (char*)d_ws;
    __hip_bfloat16* Wq = (__hip_bfloat16*)ws;                              // 32 MB
    __hip_bfloat16* xb = (__hip_bfloat16*)(ws + (size_t)32 * 1024 * 1024); // 64 MB

    // 1) merged prep: convert (16384 blocks) + dequant/fold (2048 blocks)
    prep_kernel<<<CONV_BLOCKS + DEQ_BLOCKS, 256, 0, stream>>>(
        x, qw, scales, lA, lB, xb, Wq);
    // 2) main GEMM + bias epilogue
    dim3 grid(OUT_F / 128, M_TOK / 128);           // (32, 64)
    qlora_gemm_kernel<<<grid, 256, 0, stream>>>(xb, Wq, bias, out);
}

// Round 4
// 644.452 us; speedup vs baseline: 1.8031x; 1.0361x over previous
//
#include <hip/hip_runtime.h>
#include <hip/hip_bf16.h>

#define IN_F 4096
#define OUT_F 4096
#define M_TOK 8192
#define RANK 16

#define CONV_BLOCKS (M_TOK * IN_F / (8 * 256))   // 16384
#define DEQ_BLOCKS  2048

typedef __attribute__((ext_vector_type(16))) float f32x16;
typedef __attribute__((ext_vector_type(8))) short short8;

struct alignas(16) bf16x8_s { __hip_bfloat16 v[8]; };

// ---------------------------------------------------------------------------
// Kernel 1 (merged prep) — UNCHANGED from R3:
//  blocks [0, CONV_BLOCKS): streaming convert x fp32 -> bf16
//  blocks [CONV_BLOCKS, +DEQ_BLOCKS): dequant int4 codes -> bf16 with the
//    rank-16 LoRA folded in:
//    W[o][i] = bf16( scales[o][i/64]*(q-8) + 2*sum_r A[i][r]*B[r][o] )
// ---------------------------------------------------------------------------
__global__ __launch_bounds__(256) void prep_kernel(
    const float* __restrict__ x,
    const int* __restrict__ q,
    const float* __restrict__ scales,
    const float* __restrict__ lA,   // [IN_F][RANK]
    const float* __restrict__ lB,   // [RANK][OUT_F]
    __hip_bfloat16* __restrict__ xb,
    __hip_bfloat16* __restrict__ W) {
    const int tid = threadIdx.x;

    if (blockIdx.x < CONV_BLOCKS) {
        size_t base = ((size_t)blockIdx.x * 256 + tid) * 8;
        float4 v0 = *(const float4*)(x + base);
        float4 v1 = *(const float4*)(x + base + 4);
        bf16x8_s r;
        r.v[0] = __float2bfloat16(v0.x);
        r.v[1] = __float2bfloat16(v0.y);
        r.v[2] = __float2bfloat16(v0.z);
        r.v[3] = __float2bfloat16(v0.w);
        r.v[4] = __float2bfloat16(v1.x);
        r.v[5] = __float2bfloat16(v1.y);
        r.v[6] = __float2bfloat16(v1.z);
        r.v[7] = __float2bfloat16(v1.w);
        *(bf16x8_s*)(xb + base) = r;
        return;
    }

    const int bid = blockIdx.x - CONV_BLOCKS;    // 0..2047
    const int o0 = (bid >> 1) * 4;               // block-uniform
    const int i0 = (bid & 1) * 2048 + tid * 8;

    float bw[16][4];
#pragma unroll
    for (int r = 0; r < 16; ++r)
#pragma unroll
        for (int oi = 0; oi < 4; ++oi)
            bw[r][oi] = 2.0f * lB[(size_t)r * OUT_F + o0 + oi];

    float fold[4][8];
#pragma unroll
    for (int e = 0; e < 8; ++e) {
        const float* ar = lA + (size_t)(i0 + e) * RANK;
        float4 a0 = *(const float4*)(ar + 0);
        float4 a1 = *(const float4*)(ar + 4);
        float4 a2 = *(const float4*)(ar + 8);
        float4 a3 = *(const float4*)(ar + 12);
#pragma unroll
        for (int oi = 0; oi < 4; ++oi) {
            float f = a0.x * bw[0][oi] + a0.y * bw[1][oi]
                    + a0.z * bw[2][oi] + a0.w * bw[3][oi]
                    + a1.x * bw[4][oi] + a1.y * bw[5][oi]
                    + a1.z * bw[6][oi] + a1.w * bw[7][oi]
                    + a2.x * bw[8][oi] + a2.y * bw[9][oi]
                    + a2.z * bw[10][oi] + a2.w * bw[11][oi]
                    + a3.x * bw[12][oi] + a3.y * bw[13][oi]
                    + a3.z * bw[14][oi] + a3.w * bw[15][oi];
            fold[oi][e] = f;
        }
    }

#pragma unroll
    for (int oi = 0; oi < 4; ++oi) {
        const int o = o0 + oi;
        const float s = scales[o * 64 + (i0 >> 6)];
        const int4* qp = (const int4*)(q + (size_t)o * IN_F + i0);
        int4 q0 = qp[0];
        int4 q1 = qp[1];
        bf16x8_s r;
        r.v[0] = __float2bfloat16(s * (float)(q0.x - 8) + fold[oi][0]);
        r.v[1] = __float2bfloat16(s * (float)(q0.y - 8) + fold[oi][1]);
        r.v[2] = __float2bfloat16(s * (float)(q0.z - 8) + fold[oi][2]);
        r.v[3] = __float2bfloat16(s * (float)(q0.w - 8) + fold[oi][3]);
        r.v[4] = __float2bfloat16(s * (float)(q1.x - 8) + fold[oi][4]);
        r.v[5] = __float2bfloat16(s * (float)(q1.y - 8) + fold[oi][5]);
        r.v[6] = __float2bfloat16(s * (float)(q1.z - 8) + fold[oi][6]);
        r.v[7] = __float2bfloat16(s * (float)(q1.w - 8) + fold[oi][7]);
        *(bf16x8_s*)(W + (size_t)o * IN_F + i0) = r;
    }
}

// ---------------------------------------------------------------------------
// Kernel 2: main GEMM, now on v_mfma_f32_32x32x16_bf16 (m119: +15% pipe rate,
// half the MFMA instruction count vs 16x16x32). Same 128x128 block tile,
// BK=64, 4 waves; each wave owns a 64x64 tile as 2x2 of 32x32 MFMAs.
// XOR bank swizzle carried over (conflicts stayed 0 in R2/R3 — protect it).
//   out[m][n] = sum_k xb[m][k]*W[n][k] + bias[n]
// ---------------------------------------------------------------------------
__global__ __launch_bounds__(256) void qlora_gemm_kernel(
    const __hip_bfloat16* __restrict__ xb,   // [M_TOK][IN_F]
    const __hip_bfloat16* __restrict__ Wq,   // [OUT_F][IN_F]  (B^T layout)
    const float* __restrict__ bias,          // [OUT_F]
    float* __restrict__ out) {               // [M_TOK][OUT_F]
    __shared__ __hip_bfloat16 As[128 * 64];  // 16 KB
    __shared__ __hip_bfloat16 Bs[128 * 64];  // 16 KB

    const int tid  = threadIdx.x;
    const int wave = tid >> 6;
    const int lane = tid & 63;
    const int wm = wave >> 1;                // 0..1
    const int wn = wave & 1;                 // 0..1
    const int m0 = blockIdx.y * 128;
    const int n0 = blockIdx.x * 128;

    f32x16 acc[2][2];
#pragma unroll
    for (int i = 0; i < 2; ++i)
#pragma unroll
        for (int j = 0; j < 2; ++j)
#pragma unroll
            for (int e = 0; e < 16; ++e) acc[i][j][e] = 0.f;

    // staging source: lane (sr, gc) fetches global granule (gc ^ sr) of row sr
    // so LDS position p holds global granule (p ^ (row&7))  [16B granules]
    const int sr = lane >> 3;                // 0..7 sub-row within 8-row chunk
    const int sc = ((lane & 7) ^ sr) * 8;    // swizzled 16B-granule column

    // fragment read coords (32x32x16):
    //   A[m = lane&31][k = (lane>>5)*8 + j]  -> row = base + (lane&31),
    //   granule g = ks*2 + (lane>>5), LDS pos = g ^ (row&7)
    const int frow = lane & 31;
    const int fsel = lane >> 5;              // 0..1 (k-half)

    for (int k0 = 0; k0 < IN_F; k0 += 64) {
#pragma unroll
        for (int i = 0; i < 4; ++i) {
            int c = i * 4 + wave;            // chunk 0..15 = rows [c*8, c*8+8)
            const __hip_bfloat16* ag =
                xb + (size_t)(m0 + c * 8 + sr) * IN_F + k0 + sc;
            const __hip_bfloat16* bg =
                Wq + (size_t)(n0 + c * 8 + sr) * IN_F + k0 + sc;
            __builtin_amdgcn_global_load_lds(
                (const __attribute__((address_space(1))) void*)ag,
                (__attribute__((address_space(3))) void*)(As + c * 512), 16, 0, 0);
            __builtin_amdgcn_global_load_lds(
                (const __attribute__((address_space(1))) void*)bg,
                (__attribute__((address_space(3))) void*)(Bs + c * 512), 16, 0, 0);
        }
        __syncthreads();                     // drains vmcnt before reads

        const short* Asp = (const short*)As;
        const short* Bsp = (const short*)Bs;
#pragma unroll
        for (int ks = 0; ks < 4; ++ks) {     // K=16 per step
            const int g = ks * 2 + fsel;     // 16B granule in the 64-col row
            short8 af[2], bfv[2];
#pragma unroll
            for (int t = 0; t < 2; ++t) {
                const int arow = wm * 64 + t * 32 + frow;
                const int brow = wn * 64 + t * 32 + frow;
                af[t]  = *(const short8*)(Asp + arow * 64 + ((g ^ (arow & 7)) * 8));
                bfv[t] = *(const short8*)(Bsp + brow * 64 + ((g ^ (brow & 7)) * 8));
            }
#pragma unroll
            for (int i = 0; i < 2; ++i)
#pragma unroll
                for (int j = 0; j < 2; ++j)
                    acc[i][j] = __builtin_amdgcn_mfma_f32_32x32x16_bf16(
                        af[i], bfv[j], acc[i][j], 0, 0, 0);
        }
        __syncthreads();                     // protect LDS for next stage
    }

    // ---- epilogue: bias + store
    // C/D layout (32x32): col = lane&31, row = (reg&3) + 8*(reg>>2) + 4*(lane>>5)
    const int lcol = lane & 31;
    const int rbase = 4 * (lane >> 5);
#pragma unroll
    for (int nt = 0; nt < 2; ++nt) {
        const int n = n0 + wn * 64 + nt * 32 + lcol;
        const float bv = bias[n];
#pragma unroll
        for (int mt = 0; mt < 2; ++mt) {
#pragma unroll
            for (int reg = 0; reg < 16; ++reg) {
                const int row = (reg & 3) + 8 * (reg >> 2) + rbase;
                const int m = m0 + wm * 64 + mt * 32 + row;
                out[(size_t)m * OUT_F + n] = acc[mt][nt][reg] + bv;
            }
        }
    }
}

// ---------------------------------------------------------------------------
extern "C" void kernel_launch(void* const* d_in, const int* in_sizes, int n_in,
                              void* d_out, int out_size, void* d_ws, size_t ws_size,
                              hipStream_t stream) {
    const float* x      = (const float*)d_in[0];   // [8,1024,4096] fp32
    const int*   qw     = (const int*)  d_in[1];   // [4096,4096] int32 codes
    const float* scales = (const float*)d_in[2];   // [4096,64] fp32
    const float* bias   = (const float*)d_in[3];   // [4096] fp32
    const float* lA     = (const float*)d_in[4];   // [4096,16] fp32
    const float* lB     = (const float*)d_in[5];   // [16,4096] fp32
    float* out = (float*)d_out;                    // [8,1024,4096] fp32

    // workspace layout (needs 96 MB)
    char* ws = (char*)d_ws;
    __hip_bfloat16* Wq = (__hip_bfloat16*)ws;                              // 32 MB
    __hip_bfloat16* xb = (__hip_bfloat16*)(ws + (size_t)32 * 1024 * 1024); // 64 MB

    // 1) merged prep: convert (16384 blocks) + dequant/fold (2048 blocks)
    prep_kernel<<<CONV_BLOCKS + DEQ_BLOCKS, 256, 0, stream>>>(
        x, qw, scales, lA, lB, xb, Wq);
    // 2) main GEMM + bias epilogue
    dim3 grid(OUT_F / 128, M_TOK / 128);           // (32, 64)
    qlora_gemm_kernel<<<grid, 256, 0, stream>>>(xb, Wq, bias, out);
}